// Round 2
// baseline (928.339 us; speedup 1.0000x reference)
//
#include <hip/hip_runtime.h>
#include <cstddef>
#include <cstdint>

// ---------------------------------------------------------------------------
// Swin block. Inputs/outputs f32; internal GEMMs bf16 MFMA (f32 accumulate).
// B=8 H=W=64 DIM=512 NH=16 HD=32 WS=8 SHIFT=4; tokens M=32768.
// ws layout (bytes):
//   [0, 6.0M)        qkvT/projT/fc1T/fc2T  (bf16 transposed weights)
//   [6.0M, 6.6M)     stats1, stats2        (f32 {mu,rstd} per token row)
//   [8M, 104M)       q,k,v bf16 (32MB each); attn out in-place over q;
//                    gbuf overlays k, accb overlays v (dead after attention)
// ---------------------------------------------------------------------------

typedef unsigned short u16;
typedef __attribute__((ext_vector_type(8))) short short8;
typedef __attribute__((ext_vector_type(4))) float floatx4;

__device__ __forceinline__ float bf2f(u16 u) {
    union { float f; unsigned i; } w; w.i = ((unsigned)u) << 16; return w.f;
}
__device__ __forceinline__ u16 f2bf(float f) {
    union { float f; unsigned i; } w; w.f = f;
    unsigned r = w.i + 0x7FFF + ((w.i >> 16) & 1);   // RNE
    return (u16)(r >> 16);
}

// window-token index t (win*64 + n) -> image row (b*4096 + h*64 + w) under
// the +4 cyclic shift. Serves LN1-gather (shifted window content) and the
// proj scatter (reverse shift). Bijective on [0,32768).
__device__ __forceinline__ int win_to_img_row(int t) {
    int win = t >> 6, n = t & 63;
    int b = win >> 6, wr = (win >> 3) & 7, wc = win & 7;
    int r = n >> 3, c = n & 7;
    int h = ((wr << 3) + r + 4) & 63;
    int w = ((wc << 3) + c + 4) & 63;
    return (b << 12) + (h << 6) + w;
}

// ---------------------------------------------------------------------------
// Per-row LN stats: one wave per 512-dim row -> {mu, rstd}.
// ---------------------------------------------------------------------------
__global__ __launch_bounds__(256) void ln_stats(
    const float* __restrict__ x, float* __restrict__ stats)
{
    int wave = threadIdx.x >> 6, lane = threadIdx.x & 63;
    int row = blockIdx.x * 4 + wave;
    const float* xr = x + (size_t)row * 512 + lane * 8;
    float4 a = *(const float4*)xr;
    float4 b = *(const float4*)(xr + 4);
    float s = a.x + a.y + a.z + a.w + b.x + b.y + b.z + b.w;
    float s2 = a.x*a.x + a.y*a.y + a.z*a.z + a.w*a.w
             + b.x*b.x + b.y*b.y + b.z*b.z + b.w*b.w;
#pragma unroll
    for (int off = 32; off; off >>= 1) { s += __shfl_down(s, off); s2 += __shfl_down(s2, off); }
    if (lane == 0) {
        float mu = s * (1.f / 512.f);
        float var = s2 * (1.f / 512.f) - mu * mu;
        stats[2 * row] = mu;
        stats[2 * row + 1] = rsqrtf(var + 1e-5f);
    }
}

// ---------------------------------------------------------------------------
// Weight transpose + f32->bf16: W[K,N] f32 -> WT[N,K] bf16.
// ---------------------------------------------------------------------------
__global__ __launch_bounds__(256) void transpose_k(
    const float* __restrict__ W, u16* __restrict__ WT, int K, int N)
{
    int f = blockIdx.x * 256 + threadIdx.x;     // f = kc*N + n (n fast)
    int n = f % N;
    int kc = f / N;
    if (kc >= (K >> 3)) return;
    int k0 = kc << 3;
    u16 r[8];
#pragma unroll
    for (int j = 0; j < 8; ++j) r[j] = f2bf(W[(size_t)(k0 + j) * N + n]);
    *(uint4*)(WT + (size_t)n * K + k0) = *(const uint4*)r;
}

// ---------------------------------------------------------------------------
// MFMA GEMM: C[M,N] = A * BT^T. 128x128 tile, 4 waves, 16x16x32 bf16.
// ASRC: 0 = plain bf16 A[lda];  1 = f32 x + fused LN1 + shift/window gather;
//       2 = f32 xres + fused LN2 (plain rows);  3 = bf16 q-slice gather.
// MODE epilogues as labeled.
// ---------------------------------------------------------------------------
enum { M_QKV = 0, M_PROJ = 1, M_GELU = 2, M_ACC0 = 3, M_ACC = 4, M_FINAL = 5 };

#define BK 64
#define KP 72

template <int MODE, int ASRC>
__global__ __launch_bounds__(256, 2) void gemm_bt(
    const void* __restrict__ Aptr, int lda,
    const u16* __restrict__ BT, int ldb,
    const float* __restrict__ bias,
    void* __restrict__ outp,
    const float* __restrict__ auxf, const u16* __restrict__ aux16,
    const float* __restrict__ stats,
    const float* __restrict__ lng, const float* __restrict__ lnb, int K)
{
    __shared__ __align__(16) u16 As[128 * KP];
    __shared__ __align__(16) u16 Bs[128 * KP];

    int tid = threadIdx.x;
    int bm = blockIdx.y * 128, bn = blockIdx.x * 128;
    int wave = tid >> 6, lane = tid & 63;
    int quad = lane >> 4, lr = lane & 15;
    int wm = (wave >> 1) * 64, wn = (wave & 1) * 64;

    floatx4 acc[4][4] = {};

    for (int k0 = 0; k0 < K; k0 += BK) {
#pragma unroll
        for (int l = 0; l < 4; ++l) {
            int f = (l << 8) + tid;            // 0..1023
            int row = f >> 3;
            int c8 = (f & 7) << 3;
            int kk = k0 + c8;
            // B tile (always bf16 transposed weights)
            *(uint4*)(Bs + row * KP + c8) =
                *(const uint4*)(BT + (size_t)(bn + row) * ldb + kk);
            // A tile
            if constexpr (ASRC == 0) {
                *(uint4*)(As + row * KP + c8) =
                    *(const uint4*)((const u16*)Aptr + (size_t)(bm + row) * lda + kk);
            } else if constexpr (ASRC == 3) {
                int m = bm + row;
                int win = m >> 6, tok = m & 63;
                int head = kk >> 5, d = kk & 31;
                *(uint4*)(As + row * KP + c8) =
                    *(const uint4*)((const u16*)Aptr +
                        (size_t)((win << 4) + head) * 2048 + tok * 32 + d);
            } else {
                int m = bm + row;
                int src = (ASRC == 1) ? win_to_img_row(m) : m;
                const float* xr = (const float*)Aptr + (size_t)src * 512 + kk;
                float4 v0 = *(const float4*)xr;
                float4 v1 = *(const float4*)(xr + 4);
                float mu = stats[2 * src], rs = stats[2 * src + 1];
                float4 g0 = *(const float4*)(lng + kk);
                float4 g1 = *(const float4*)(lng + kk + 4);
                float4 b0 = *(const float4*)(lnb + kk);
                float4 b1 = *(const float4*)(lnb + kk + 4);
                u16 r[8];
                r[0] = f2bf((v0.x - mu) * rs * g0.x + b0.x);
                r[1] = f2bf((v0.y - mu) * rs * g0.y + b0.y);
                r[2] = f2bf((v0.z - mu) * rs * g0.z + b0.z);
                r[3] = f2bf((v0.w - mu) * rs * g0.w + b0.w);
                r[4] = f2bf((v1.x - mu) * rs * g1.x + b1.x);
                r[5] = f2bf((v1.y - mu) * rs * g1.y + b1.y);
                r[6] = f2bf((v1.z - mu) * rs * g1.z + b1.z);
                r[7] = f2bf((v1.w - mu) * rs * g1.w + b1.w);
                *(uint4*)(As + row * KP + c8) = *(const uint4*)r;
            }
        }
        __syncthreads();
#pragma unroll
        for (int step = 0; step < 2; ++step) {
            int ko = (step << 5) + (quad << 3);
            short8 af[4], bv[4];
#pragma unroll
            for (int t = 0; t < 4; ++t) {
                af[t] = *(const short8*)(As + (wm + t * 16 + lr) * KP + ko);
                bv[t] = *(const short8*)(Bs + (wn + t * 16 + lr) * KP + ko);
            }
#pragma unroll
            for (int mt = 0; mt < 4; ++mt)
#pragma unroll
                for (int nt = 0; nt < 4; ++nt)
                    acc[mt][nt] = __builtin_amdgcn_mfma_f32_16x16x32_bf16(
                        af[mt], bv[nt], acc[mt][nt], 0, 0, 0);
        }
        __syncthreads();
    }

    // epilogue: D row = quad*4+i, col = lr (per 16x16 tile)
#pragma unroll
    for (int mt = 0; mt < 4; ++mt) {
#pragma unroll
        for (int nt = 0; nt < 4; ++nt) {
            int m0 = bm + wm + mt * 16 + quad * 4;
            int n = bn + wn + nt * 16 + lr;
#pragma unroll
            for (int i = 0; i < 4; ++i) {
                int m = m0 + i;
                float v = acc[mt][nt][i];
                if constexpr (MODE == M_QKV) {
                    v += bias[n];
                    int sel = n >> 9, head = (n >> 5) & 15, d = n & 31;
                    int wh = (m >> 6) * 16 + head, tok = m & 63;
                    ((u16*)outp)[(size_t)sel * 16777216 + (size_t)wh * 2048 + tok * 32 + d] = f2bf(v);
                } else if constexpr (MODE == M_PROJ) {
                    size_t idx = (size_t)win_to_img_row(m) * 512 + n;
                    ((float*)outp)[idx] = v + bias[n] + auxf[idx];
                } else if constexpr (MODE == M_GELU) {
                    v += bias[n];
                    float gel = 0.5f * v * (1.0f + erff(v * 0.70710678118654752f));
                    ((u16*)outp)[(size_t)m * 512 + n] = f2bf(gel);
                } else if constexpr (MODE == M_ACC0) {
                    ((u16*)outp)[(size_t)m * 512 + n] = f2bf(v);
                } else if constexpr (MODE == M_ACC) {
                    size_t idx = (size_t)m * 512 + n;
                    u16* o = (u16*)outp;
                    o[idx] = f2bf(bf2f(o[idx]) + v);
                } else { // M_FINAL: outp = xres (f32), aux16 = bf16 partial acc
                    size_t idx = (size_t)m * 512 + n;
                    float* o = (float*)outp;
                    o[idx] = o[idx] + bf2f(aux16[idx]) + v + bias[n];
                }
            }
        }
    }
}

// ---------------------------------------------------------------------------
// Windowed attention, one wave per (window, head). Scalar fp32 math.
// q/k/v: bf16 [win*16+head][64 tok][32 d]. Output written in-place over the
// block's own q slice (each lane reads its q row into regs before writing).
// ---------------------------------------------------------------------------
__global__ __launch_bounds__(64) void attn_kernel(
    const u16* __restrict__ qkv, const float* __restrict__ table,
    u16* __restrict__ outp)
{
    __shared__ __align__(16) float klds[64][36];
    __shared__ __align__(16) float vlds[64][36];
    __shared__ float slds[64][65];
    __shared__ float blds[225];

    int wh = blockIdx.x, win = wh >> 4, head = wh & 15;
    int lane = threadIdx.x;
    const u16* qb = qkv + (size_t)wh * 2048;
    const u16* kb = qb + 16777216;
    const u16* vb = qb + 33554432;

#pragma unroll
    for (int l = 0; l < 4; ++l) {
        int f = l * 64 + lane;                 // 256 chunks of 8
        int row = f >> 2, c8 = (f & 3) << 3;
        uint4 rk = *(const uint4*)(kb + row * 32 + c8);
        uint4 rv = *(const uint4*)(vb + row * 32 + c8);
        const u16* pk = (const u16*)&rk;
        const u16* pv = (const u16*)&rv;
#pragma unroll
        for (int j = 0; j < 8; ++j) {
            klds[row][c8 + j] = bf2f(pk[j]);
            vlds[row][c8 + j] = bf2f(pv[j]);
        }
    }
    for (int idx = lane; idx < 225; idx += 64) blds[idx] = table[idx * 16 + head];

    float qreg[32];
    const u16* qr = qb + lane * 32;
#pragma unroll
    for (int c = 0; c < 4; ++c) {
        uint4 r = *(const uint4*)(qr + c * 8);
        const u16* p = (const u16*)&r;
#pragma unroll
        for (int j = 0; j < 8; ++j) qreg[c * 8 + j] = bf2f(p[j]) * 0.17677669529663687f;
    }
    __syncthreads();

    int i = lane, ri = i >> 3, ci = i & 7;
    int wr = (win >> 3) & 7, wc = win & 7;
    int hI = wr * 8 + ri, wI = wc * 8 + ci;
    int regi = (hI < 56 ? 0 : (hI < 60 ? 1 : 2)) * 3 + (wI < 56 ? 0 : (wI < 60 ? 1 : 2));

    float smax = -1e30f;
    for (int j = 0; j < 64; ++j) {
        float s0 = 0.f, s1 = 0.f, s2 = 0.f, s3 = 0.f;
#pragma unroll
        for (int d = 0; d < 32; d += 4) {
            s0 += qreg[d] * klds[j][d];
            s1 += qreg[d + 1] * klds[j][d + 1];
            s2 += qreg[d + 2] * klds[j][d + 2];
            s3 += qreg[d + 3] * klds[j][d + 3];
        }
        float s = (s0 + s1) + (s2 + s3);
        int rj = j >> 3, cj = j & 7;
        s += blds[(ri - rj + 7) * 15 + (ci - cj + 7)];
        int hJ = wr * 8 + rj, wJ = wc * 8 + cj;
        int regj = (hJ < 56 ? 0 : (hJ < 60 ? 1 : 2)) * 3 + (wJ < 56 ? 0 : (wJ < 60 ? 1 : 2));
        if (regj != regi) s -= 100.f;
        slds[i][j] = s;
        smax = fmaxf(smax, s);
    }
    float ssum = 0.f;
    for (int j = 0; j < 64; ++j) {
        float e = __expf(slds[i][j] - smax);
        slds[i][j] = e;
        ssum += e;
    }
    float inv = 1.f / ssum;

    float o[32];
#pragma unroll
    for (int d = 0; d < 32; ++d) o[d] = 0.f;
    for (int j = 0; j < 64; ++j) {
        float p = slds[i][j];
#pragma unroll
        for (int d = 0; d < 32; ++d) o[d] += p * vlds[j][d];
    }
    u16 res[32];
#pragma unroll
    for (int d = 0; d < 32; ++d) res[d] = f2bf(o[d] * inv);
    u16* dst = outp + (size_t)wh * 2048 + i * 32;   // in-place over own q slice
#pragma unroll
    for (int c = 0; c < 4; ++c) *(uint4*)(dst + c * 8) = *(const uint4*)(res + c * 8);
}

// ---------------------------------------------------------------------------
extern "C" void kernel_launch(void* const* d_in, const int* in_sizes, int n_in,
                              void* d_out, int out_size, void* d_ws, size_t ws_size,
                              hipStream_t stream)
{
    (void)in_sizes; (void)n_in; (void)out_size; (void)ws_size;
    const float* x      = (const float*)d_in[0];
    // d_in[1] fundamental_context: unused by the reference
    const float* n1g    = (const float*)d_in[2];
    const float* n1b    = (const float*)d_in[3];
    const float* qkv_w  = (const float*)d_in[4];
    const float* qkv_b  = (const float*)d_in[5];
    const float* table  = (const float*)d_in[6];
    const float* proj_w = (const float*)d_in[7];
    const float* proj_b = (const float*)d_in[8];
    const float* n2g    = (const float*)d_in[9];
    const float* n2b    = (const float*)d_in[10];
    const float* fc1_w  = (const float*)d_in[11];
    const float* fc1_b  = (const float*)d_in[12];
    const float* fc2_w  = (const float*)d_in[13];
    const float* fc2_b  = (const float*)d_in[14];
    float* out = (float*)d_out;
    char* ws = (char*)d_ws;

    u16* qkvT  = (u16*)ws;                  // 786432 elems
    u16* projT = qkvT + 786432;             // 262144
    u16* fc1T  = projT + 262144;            // 1048576
    u16* fc2T  = fc1T + 1048576;            // 1048576  (ends at 6,291,456 B)
    float* stats1 = (float*)(ws + 6291456); // 65536 f32
    float* stats2 = stats1 + 65536;         // ends at 6,815,744 B
    u16* q    = (u16*)(ws + 8388608);       // q,k,v: 3 x 32MB -> ends 104 MB
    u16* gbuf = q + 16777216;               // overlays k (dead after attn)
    u16* accb = q + 2 * 16777216;           // overlays v (dead after attn)

    // bf16 transposed weights
    transpose_k<<<384, 256, 0, stream>>>(qkv_w, qkvT, 512, 1536);
    transpose_k<<<128, 256, 0, stream>>>(proj_w, projT, 512, 512);
    transpose_k<<<512, 256, 0, stream>>>(fc1_w, fc1T, 512, 2048);
    transpose_k<<<512, 256, 0, stream>>>(fc2_w, fc2T, 2048, 512);

    // LN1 stats on x rows
    ln_stats<<<8192, 256, 0, stream>>>(x, stats1);
    // QKV (LN1 + shift/window fused into A staging)
    gemm_bt<M_QKV, 1><<<dim3(12, 256), 256, 0, stream>>>(
        x, 0, qkvT, 512, qkv_b, q, nullptr, nullptr, stats1, n1g, n1b, 512);
    // attention (writes in-place over q slices)
    attn_kernel<<<8192, 64, 0, stream>>>(q, table, q);
    // proj + window-reverse/unshift + residual -> d_out (f32 xres)
    gemm_bt<M_PROJ, 3><<<dim3(4, 256), 256, 0, stream>>>(
        q, 0, projT, 512, proj_b, out, x, nullptr, nullptr, nullptr, nullptr, 512);
    // LN2 stats on xres
    ln_stats<<<8192, 256, 0, stream>>>(out, stats2);
    // MLP: hidden chunked 4 x 512 (fc1+GELU -> gbuf; fc2 accumulated in accb)
    gemm_bt<M_GELU, 2><<<dim3(4, 256), 256, 0, stream>>>(
        out, 0, fc1T + 0 * 262144, 512, fc1_b + 0, gbuf, nullptr, nullptr, stats2, n2g, n2b, 512);
    gemm_bt<M_ACC0, 0><<<dim3(4, 256), 256, 0, stream>>>(
        gbuf, 512, fc2T + 0 * 512, 2048, nullptr, accb, nullptr, nullptr, nullptr, nullptr, nullptr, 512);
    gemm_bt<M_GELU, 2><<<dim3(4, 256), 256, 0, stream>>>(
        out, 0, fc1T + 1 * 262144, 512, fc1_b + 512, gbuf, nullptr, nullptr, stats2, n2g, n2b, 512);
    gemm_bt<M_ACC, 0><<<dim3(4, 256), 256, 0, stream>>>(
        gbuf, 512, fc2T + 1 * 512, 2048, nullptr, accb, nullptr, nullptr, nullptr, nullptr, nullptr, 512);
    gemm_bt<M_GELU, 2><<<dim3(4, 256), 256, 0, stream>>>(
        out, 0, fc1T + 2 * 262144, 512, fc1_b + 1024, gbuf, nullptr, nullptr, stats2, n2g, n2b, 512);
    gemm_bt<M_ACC, 0><<<dim3(4, 256), 256, 0, stream>>>(
        gbuf, 512, fc2T + 2 * 512, 2048, nullptr, accb, nullptr, nullptr, nullptr, nullptr, nullptr, 512);
    gemm_bt<M_GELU, 2><<<dim3(4, 256), 256, 0, stream>>>(
        out, 0, fc1T + 3 * 262144, 512, fc1_b + 1536, gbuf, nullptr, nullptr, stats2, n2g, n2b, 512);
    // final fc2 chunk: xres + acc + v + fc2_b -> d_out
    gemm_bt<M_FINAL, 0><<<dim3(4, 256), 256, 0, stream>>>(
        gbuf, 512, fc2T + 3 * 512, 2048, fc2_b, out, nullptr, accb, nullptr, nullptr, nullptr, 512);
}

// Round 3
// 779.572 us; speedup vs baseline: 1.1908x; 1.1908x over previous
//
#include <hip/hip_runtime.h>
#include <cstddef>
#include <cstdint>

// ---------------------------------------------------------------------------
// Swin block. f32 in/out; internal bf16 MFMA. B=8 H=W=64 DIM=512 NH=16 HD=32.
// ws: [0,6.3M) bf16 weights | [6.3,6.9M) stats | q[8,40) k[40,72) v[72,104) MB
//     h2 overlays q after proj; gbuf (16384x2048 bf16, 64MB) overlays k+v.
// ---------------------------------------------------------------------------

typedef unsigned short u16;
typedef __attribute__((ext_vector_type(8))) short short8;
typedef __attribute__((ext_vector_type(4))) float floatx4;

__device__ __forceinline__ float bf2f(u16 u) {
    union { float f; unsigned i; } w; w.i = ((unsigned)u) << 16; return w.f;
}
__device__ __forceinline__ u16 f2bf(float f) {
    union { float f; unsigned i; } w; w.f = f;
    unsigned r = w.i + 0x7FFF + ((w.i >> 16) & 1);   // RNE
    return (u16)(r >> 16);
}

// async 16B global->LDS (CK-proven addrspace-cast idiom)
__device__ __forceinline__ void async_cp16(const void* g, void* l) {
    __builtin_amdgcn_global_load_lds(
        (const __attribute__((address_space(1))) unsigned*)(uintptr_t)g,
        (__attribute__((address_space(3))) unsigned*)(uintptr_t)l, 16, 0, 0);
}

__device__ __forceinline__ int win_to_img_row(int t) {
    int win = t >> 6, n = t & 63;
    int b = win >> 6, wr = (win >> 3) & 7, wc = win & 7;
    int h = ((wr << 3) + (n >> 3) + 4) & 63;
    int w = ((wc << 3) + (n & 7) + 4) & 63;
    return (b << 12) + (h << 6) + w;
}

// ---------------------------------------------------------------------------
__global__ __launch_bounds__(256) void ln_stats(
    const float* __restrict__ x, float* __restrict__ stats)
{
    int wave = threadIdx.x >> 6, lane = threadIdx.x & 63;
    int row = blockIdx.x * 4 + wave;
    const float* xr = x + (size_t)row * 512 + lane * 8;
    float4 a = *(const float4*)xr;
    float4 b = *(const float4*)(xr + 4);
    float s = a.x + a.y + a.z + a.w + b.x + b.y + b.z + b.w;
    float s2 = a.x*a.x + a.y*a.y + a.z*a.z + a.w*a.w
             + b.x*b.x + b.y*b.y + b.z*b.z + b.w*b.w;
#pragma unroll
    for (int off = 32; off; off >>= 1) { s += __shfl_down(s, off); s2 += __shfl_down(s2, off); }
    if (lane == 0) {
        float mu = s * (1.f / 512.f);
        float var = s2 * (1.f / 512.f) - mu * mu;
        stats[2 * row] = mu;
        stats[2 * row + 1] = rsqrtf(var + 1e-5f);
    }
}

// LN apply -> bf16 rows (for MLP input h2)
__global__ __launch_bounds__(256) void ln_apply(
    const float* __restrict__ x, const float* __restrict__ stats,
    const float* __restrict__ g, const float* __restrict__ b,
    u16* __restrict__ out)
{
    int idx = blockIdx.x * 256 + threadIdx.x;     // 8 elems each
    int row = idx >> 6, col = (idx & 63) << 3;
    const float* xr = x + (size_t)row * 512 + col;
    float4 v0 = *(const float4*)xr;
    float4 v1 = *(const float4*)(xr + 4);
    float mu = stats[2 * row], rs = stats[2 * row + 1];
    float4 g0 = *(const float4*)(g + col), g1 = *(const float4*)(g + col + 4);
    float4 b0 = *(const float4*)(b + col), b1 = *(const float4*)(b + col + 4);
    u16 r[8];
    r[0] = f2bf((v0.x - mu) * rs * g0.x + b0.x);
    r[1] = f2bf((v0.y - mu) * rs * g0.y + b0.y);
    r[2] = f2bf((v0.z - mu) * rs * g0.z + b0.z);
    r[3] = f2bf((v0.w - mu) * rs * g0.w + b0.w);
    r[4] = f2bf((v1.x - mu) * rs * g1.x + b1.x);
    r[5] = f2bf((v1.y - mu) * rs * g1.y + b1.y);
    r[6] = f2bf((v1.z - mu) * rs * g1.z + b1.z);
    r[7] = f2bf((v1.w - mu) * rs * g1.w + b1.w);
    *(uint4*)(out + (size_t)row * 512 + col) = *(const uint4*)r;
}

__global__ __launch_bounds__(256) void transpose_k(
    const float* __restrict__ W, u16* __restrict__ WT, int K, int N)
{
    int f = blockIdx.x * 256 + threadIdx.x;
    int n = f % N, kc = f / N;
    if (kc >= (K >> 3)) return;
    int k0 = kc << 3;
    u16 r[8];
#pragma unroll
    for (int j = 0; j < 8; ++j) r[j] = f2bf(W[(size_t)(k0 + j) * N + n]);
    *(uint4*)(WT + (size_t)n * K + k0) = *(const uint4*)r;
}

// ---------------------------------------------------------------------------
// MFMA GEMM, 128x128 tile, BK=64, chunk-major LDS (stride 1032 u16 = 2064 B):
// element (row, k=c*8+j) at [c*1032 + row*8 + j]. Conflict-free for b128 frag
// reads, manual uint4 writes, and matches global_load_lds lane*16 placement.
// ASRC: 0 plain bf16 (async) | 1 f32 + fused LN + shift gather (manual)
//     | 3 bf16 qkv-slice gather (async).
// ---------------------------------------------------------------------------
enum { M_QKV = 0, M_PROJ = 1, M_GELU = 2, M_FINAL = 3 };

template <int MODE, int ASRC>
__global__ __launch_bounds__(256, 2) void gemm_bt(
    const void* __restrict__ Aptr, int lda,
    const u16* __restrict__ BT, int ldb,
    const float* __restrict__ bias,
    void* __restrict__ outp, const float* __restrict__ auxf,
    const float* __restrict__ stats,
    const float* __restrict__ lng, const float* __restrict__ lnb, int K)
{
    __shared__ __align__(16) u16 As[8 * 1032];
    __shared__ __align__(16) u16 Bs[8 * 1032];

    int tid = threadIdx.x;
    int bm = blockIdx.y * 128, bn = blockIdx.x * 128;
    int wave = tid >> 6, lane = tid & 63;
    int quad = lane >> 4, lr = lane & 15;
    int wm = (wave >> 1) * 64, wn = (wave & 1) * 64;

    floatx4 acc[4][4] = {};

    for (int k0 = 0; k0 < K; k0 += 64) {
#pragma unroll
        for (int l = 0; l < 4; ++l) {
            int idx = wave * 4 + l;            // 0..15
            int c = idx & 7, half = idx >> 3;
            int kk = k0 + c * 8;
            // B tile: always async
            async_cp16(BT + (size_t)(bn + half * 64 + lane) * ldb + kk,
                       Bs + c * 1032 + half * 512);
            if constexpr (ASRC == 0) {
                async_cp16((const u16*)Aptr + (size_t)(bm + half * 64 + lane) * lda + kk,
                           As + c * 1032 + half * 512);
            } else if constexpr (ASRC == 3) {
                // q-slice gather: win uniform per (half), tok = lane
                int win = (bm >> 6) + half;
                async_cp16((const u16*)Aptr + (size_t)((win << 4) + (kk >> 5)) * 2048
                               + lane * 32 + (kk & 31),
                           As + c * 1032 + half * 512);
            }
        }
        if constexpr (ASRC == 1) {
#pragma unroll
            for (int l = 0; l < 4; ++l) {
                int f = (l << 8) + tid;
                int row = f >> 3, c = f & 7;
                int kk = k0 + c * 8;
                int src = win_to_img_row(bm + row);
                const float* xr = (const float*)Aptr + (size_t)src * 512 + kk;
                float4 v0 = *(const float4*)xr;
                float4 v1 = *(const float4*)(xr + 4);
                float mu = stats[2 * src], rs = stats[2 * src + 1];
                float4 g0 = *(const float4*)(lng + kk), g1 = *(const float4*)(lng + kk + 4);
                float4 b0 = *(const float4*)(lnb + kk), b1 = *(const float4*)(lnb + kk + 4);
                u16 r[8];
                r[0] = f2bf((v0.x - mu) * rs * g0.x + b0.x);
                r[1] = f2bf((v0.y - mu) * rs * g0.y + b0.y);
                r[2] = f2bf((v0.z - mu) * rs * g0.z + b0.z);
                r[3] = f2bf((v0.w - mu) * rs * g0.w + b0.w);
                r[4] = f2bf((v1.x - mu) * rs * g1.x + b1.x);
                r[5] = f2bf((v1.y - mu) * rs * g1.y + b1.y);
                r[6] = f2bf((v1.z - mu) * rs * g1.z + b1.z);
                r[7] = f2bf((v1.w - mu) * rs * g1.w + b1.w);
                *(uint4*)(As + c * 1032 + row * 8) = *(const uint4*)r;
            }
        }
        __syncthreads();
#pragma unroll
        for (int step = 0; step < 2; ++step) {
            short8 af[4], bv[4];
#pragma unroll
            for (int t = 0; t < 4; ++t) {
                int kc = step * 4 + quad;
                af[t] = *(const short8*)(As + kc * 1032 + (wm + t * 16 + lr) * 8);
                bv[t] = *(const short8*)(Bs + kc * 1032 + (wn + t * 16 + lr) * 8);
            }
#pragma unroll
            for (int mt = 0; mt < 4; ++mt)
#pragma unroll
                for (int nt = 0; nt < 4; ++nt)
                    acc[mt][nt] = __builtin_amdgcn_mfma_f32_16x16x32_bf16(
                        af[mt], bv[nt], acc[mt][nt], 0, 0, 0);
        }
        __syncthreads();
    }

#pragma unroll
    for (int mt = 0; mt < 4; ++mt) {
#pragma unroll
        for (int nt = 0; nt < 4; ++nt) {
            int m0 = bm + wm + mt * 16 + quad * 4;
            int n = bn + wn + nt * 16 + lr;
#pragma unroll
            for (int i = 0; i < 4; ++i) {
                int m = m0 + i;
                float v = acc[mt][nt][i];
                if constexpr (MODE == M_QKV) {
                    v += bias[n];
                    int sel = n >> 9, head = (n >> 5) & 15, d = n & 31;
                    int wh = (m >> 6) * 16 + head, tok = m & 63;
                    ((u16*)outp)[(size_t)sel * 16777216 + (size_t)wh * 2048 + tok * 32 + d] = f2bf(v);
                } else if constexpr (MODE == M_PROJ) {
                    size_t idx = (size_t)win_to_img_row(m) * 512 + n;
                    ((float*)outp)[idx] = v + bias[n] + auxf[idx];
                } else if constexpr (MODE == M_GELU) {
                    v += bias[n];
                    float gel = 0.5f * v * (1.0f + erff(v * 0.70710678118654752f));
                    ((u16*)outp)[(size_t)m * 2048 + n] = f2bf(gel);
                } else { // M_FINAL: outp = xres f32, read-modify-write
                    size_t idx = (size_t)m * 512 + n;
                    float* o = (float*)outp;
                    o[idx] = o[idx] + v + bias[n];
                }
            }
        }
    }
}

// ---------------------------------------------------------------------------
// MFMA attention: block = 4 waves = 4 windows x 1 shared head; wave handles
// one (win,head): S = Q K^T (16 mfma), softmax in C-layout (rows live inside
// a quad -> shfl_xor over {1,2,4,8}), P -> LDS transposed bf16 (b64-packed
// writes, row stride 76 u16), O = P V (16 mfma). Output in-place over q.
// ---------------------------------------------------------------------------
__global__ __launch_bounds__(256) void attn_mfma(
    const u16* __restrict__ qkv, const float* __restrict__ table,
    u16* __restrict__ outp)
{
    __shared__ __align__(8) u16 PT[4][64 * 76];
    __shared__ float blds[225];

    int w = threadIdx.x >> 6, lane = threadIdx.x & 63;
    int head = blockIdx.x & 15, win = ((blockIdx.x >> 4) << 2) + w;
    int wh = (win << 4) + head;
    int quad = lane >> 4, lr = lane & 15;
    const u16* qb = qkv + (size_t)wh * 2048;
    const u16* kb = qb + 16777216;
    const u16* vb = qb + 33554432;
    u16* PTw = PT[w];

    for (int i = threadIdx.x; i < 225; i += 256) blds[i] = table[i * 16 + head];
    __syncthreads();

    // ---- S = Q K^T ----
    short8 qf[4], kf[4];
#pragma unroll
    for (int t = 0; t < 4; ++t) {
        qf[t] = *(const short8*)(qb + (t * 16 + lr) * 32 + quad * 8);
        kf[t] = *(const short8*)(kb + (t * 16 + lr) * 32 + quad * 8);
    }
    floatx4 s[4][4] = {};
#pragma unroll
    for (int mi = 0; mi < 4; ++mi)
#pragma unroll
        for (int ni = 0; ni < 4; ++ni)
            s[mi][ni] = __builtin_amdgcn_mfma_f32_16x16x32_bf16(qf[mi], kf[ni], s[mi][ni], 0, 0, 0);

    // V fragments early (overlap latency): vf[kstep][nd]
    short8 vf[2][2];
#pragma unroll
    for (int ks = 0; ks < 2; ++ks)
#pragma unroll
        for (int nd = 0; nd < 2; ++nd)
#pragma unroll
            for (int j = 0; j < 8; ++j)
                vf[ks][nd][j] = (short)vb[(ks * 32 + quad * 8 + j) * 32 + nd * 16 + lr];

    // ---- scale + rel-bias + region mask ----
    int wr = (win >> 3) & 7, wc = win & 7;
    int rj[4], cj[4], regj[4];
#pragma unroll
    for (int ni = 0; ni < 4; ++ni) {
        int kj = ni * 16 + lr;
        rj[ni] = kj >> 3; cj[ni] = kj & 7;
        int hJ = wr * 8 + rj[ni], wJ = wc * 8 + cj[ni];
        regj[ni] = (hJ < 56 ? 0 : (hJ < 60 ? 1 : 2)) * 3 + (wJ < 56 ? 0 : (wJ < 60 ? 1 : 2));
    }
    float rm[4][4], linv[4][4];
#pragma unroll
    for (int mi = 0; mi < 4; ++mi) {
#pragma unroll
        for (int i = 0; i < 4; ++i) {
            int qi = mi * 16 + quad * 4 + i;
            int ri = qi >> 3, ci = qi & 7;
            int hI = wr * 8 + ri, wI = wc * 8 + ci;
            int regi = (hI < 56 ? 0 : (hI < 60 ? 1 : 2)) * 3 + (wI < 56 ? 0 : (wI < 60 ? 1 : 2));
            float mx = -1e30f;
#pragma unroll
            for (int ni = 0; ni < 4; ++ni) {
                float v = s[mi][ni][i] * 0.17677669529663687f
                        + blds[(ri - rj[ni] + 7) * 15 + (ci - cj[ni] + 7)];
                if (regj[ni] != regi) v -= 100.f;
                s[mi][ni][i] = v;
                mx = fmaxf(mx, v);
            }
            rm[mi][i] = mx;
        }
    }
    // row reductions within quad (lanes differing in low-4 bits share quad)
#pragma unroll
    for (int mi = 0; mi < 4; ++mi)
#pragma unroll
        for (int i = 0; i < 4; ++i) {
            float mx = rm[mi][i];
#pragma unroll
            for (int msk = 1; msk < 16; msk <<= 1) mx = fmaxf(mx, __shfl_xor(mx, msk));
            float sum = 0.f;
#pragma unroll
            for (int ni = 0; ni < 4; ++ni) {
                float e = __expf(s[mi][ni][i] - mx);
                s[mi][ni][i] = e;
                sum += e;
            }
#pragma unroll
            for (int msk = 1; msk < 16; msk <<= 1) sum += __shfl_xor(sum, msk);
            linv[mi][i] = 1.f / sum;
        }

    // ---- P -> LDS transposed (PT[col kj][row qi]), b64-packed over i ----
#pragma unroll
    for (int mi = 0; mi < 4; ++mi)
#pragma unroll
        for (int ni = 0; ni < 4; ++ni) {
            unsigned lo = (unsigned)f2bf(s[mi][ni][0]) | ((unsigned)f2bf(s[mi][ni][1]) << 16);
            unsigned hi = (unsigned)f2bf(s[mi][ni][2]) | ((unsigned)f2bf(s[mi][ni][3]) << 16);
            uint2 pk = make_uint2(lo, hi);
            *(uint2*)(PTw + (ni * 16 + lr) * 76 + mi * 16 + quad * 4) = pk;
        }
    __syncthreads();   // cheap; also orders per-wave LDS write->read

    // ---- O = P V ----
    floatx4 o[4][2] = {};
#pragma unroll
    for (int mi = 0; mi < 4; ++mi) {
#pragma unroll
        for (int ks = 0; ks < 2; ++ks) {
            short8 pa;
#pragma unroll
            for (int j = 0; j < 8; ++j)
                pa[j] = (short)PTw[(ks * 32 + quad * 8 + j) * 76 + mi * 16 + lr];
#pragma unroll
            for (int nd = 0; nd < 2; ++nd)
                o[mi][nd] = __builtin_amdgcn_mfma_f32_16x16x32_bf16(pa, vf[ks][nd], o[mi][nd], 0, 0, 0);
        }
    }
    // ---- write (in-place over own q slice; all q reads done) ----
    u16* ob = outp + (size_t)wh * 2048;
#pragma unroll
    for (int mi = 0; mi < 4; ++mi)
#pragma unroll
        for (int nd = 0; nd < 2; ++nd)
#pragma unroll
            for (int i = 0; i < 4; ++i) {
                int qi = mi * 16 + quad * 4 + i;
                ob[qi * 32 + nd * 16 + lr] = f2bf(o[mi][nd][i] * linv[mi][i]);
            }
}

// ---------------------------------------------------------------------------
extern "C" void kernel_launch(void* const* d_in, const int* in_sizes, int n_in,
                              void* d_out, int out_size, void* d_ws, size_t ws_size,
                              hipStream_t stream)
{
    (void)in_sizes; (void)n_in; (void)out_size; (void)ws_size;
    const float* x      = (const float*)d_in[0];
    const float* n1g    = (const float*)d_in[2];
    const float* n1b    = (const float*)d_in[3];
    const float* qkv_w  = (const float*)d_in[4];
    const float* qkv_b  = (const float*)d_in[5];
    const float* table  = (const float*)d_in[6];
    const float* proj_w = (const float*)d_in[7];
    const float* proj_b = (const float*)d_in[8];
    const float* n2g    = (const float*)d_in[9];
    const float* n2b    = (const float*)d_in[10];
    const float* fc1_w  = (const float*)d_in[11];
    const float* fc1_b  = (const float*)d_in[12];
    const float* fc2_w  = (const float*)d_in[13];
    const float* fc2_b  = (const float*)d_in[14];
    float* out = (float*)d_out;
    char* ws = (char*)d_ws;

    u16* qkvT  = (u16*)ws;                  // 786432
    u16* projT = qkvT + 786432;             // 262144
    u16* fc1T  = projT + 262144;            // 1048576
    u16* fc2T  = fc1T + 1048576;            // 1048576 (ends 6,291,456 B)
    float* stats1 = (float*)(ws + 6291456);
    float* stats2 = stats1 + 65536;
    u16* q    = (u16*)(ws + 8388608);       // q,k,v 3x32MB (ends 104 MB)
    u16* h2   = q;                          // overlays q after proj
    u16* gbuf = q + 16777216;               // 64 MB over k+v (dead post-attn)

    transpose_k<<<384, 256, 0, stream>>>(qkv_w, qkvT, 512, 1536);
    transpose_k<<<128, 256, 0, stream>>>(proj_w, projT, 512, 512);
    transpose_k<<<512, 256, 0, stream>>>(fc1_w, fc1T, 512, 2048);
    transpose_k<<<512, 256, 0, stream>>>(fc2_w, fc2T, 2048, 512);

    ln_stats<<<8192, 256, 0, stream>>>(x, stats1);
    gemm_bt<M_QKV, 1><<<dim3(12, 256), 256, 0, stream>>>(
        x, 0, qkvT, 512, qkv_b, q, nullptr, stats1, n1g, n1b, 512);
    attn_mfma<<<2048, 256, 0, stream>>>(q, table, q);
    gemm_bt<M_PROJ, 3><<<dim3(4, 256), 256, 0, stream>>>(
        q, 0, projT, 512, proj_b, out, x, nullptr, nullptr, nullptr, 512);
    ln_stats<<<8192, 256, 0, stream>>>(out, stats2);
    ln_apply<<<8192, 256, 0, stream>>>(out, stats2, n2g, n2b, h2);
    for (int mc = 0; mc < 2; ++mc) {
        gemm_bt<M_GELU, 0><<<dim3(16, 128), 256, 0, stream>>>(
            h2 + (size_t)mc * 16384 * 512, 512, fc1T, 512, fc1_b,
            gbuf, nullptr, nullptr, nullptr, nullptr, 512);
        gemm_bt<M_FINAL, 0><<<dim3(4, 128), 256, 0, stream>>>(
            gbuf, 2048, fc2T, 2048, fc2_b,
            out + (size_t)mc * 16384 * 512, nullptr, nullptr, nullptr, nullptr, 2048);
    }
}

// Round 4
// 738.280 us; speedup vs baseline: 1.2574x; 1.0559x over previous
//
#include <hip/hip_runtime.h>
#include <cstddef>
#include <cstdint>

// ---------------------------------------------------------------------------
// Swin block. f32 in/out; internal bf16 MFMA. B=8 H=W=64 DIM=512 NH=16 HD=32.
// ws: [0,6.3M) bf16 weights | q[8,40) k[40,72) v[72,104) MB
//     h2 overlays q after proj; gbuf (16384x2048 bf16, 64MB) overlays k+v.
// xw (LN1+shift, bf16 32MB) lives in d_out (dead until proj overwrites it).
// ---------------------------------------------------------------------------

typedef unsigned short u16;
typedef __attribute__((ext_vector_type(8))) short short8;
typedef __attribute__((ext_vector_type(4))) float floatx4;

__device__ __forceinline__ float bf2f(u16 u) {
    union { float f; unsigned i; } w; w.i = ((unsigned)u) << 16; return w.f;
}
__device__ __forceinline__ u16 f2bf(float f) {
    union { float f; unsigned i; } w; w.f = f;
    unsigned r = w.i + 0x7FFF + ((w.i >> 16) & 1);   // RNE
    return (u16)(r >> 16);
}

// async 16B global->LDS
__device__ __forceinline__ void async_cp16(const void* g, void* l) {
    __builtin_amdgcn_global_load_lds(
        (const __attribute__((address_space(1))) unsigned*)(uintptr_t)g,
        (__attribute__((address_space(3))) unsigned*)(uintptr_t)l, 16, 0, 0);
}

__device__ __forceinline__ int win_to_img_row(int t) {
    int win = t >> 6, n = t & 63;
    int b = win >> 6, wr = (win >> 3) & 7, wc = win & 7;
    int h = ((wr << 3) + (n >> 3) + 4) & 63;
    int w = ((wc << 3) + (n & 7) + 4) & 63;
    return (b << 12) + (h << 6) + w;
}

// ---------------------------------------------------------------------------
// Fused LayerNorm: one wave per 512-dim row, single pass (stats via shuffle,
// apply, write bf16). gather=1: row t reads shifted/windowed source row.
// ---------------------------------------------------------------------------
__global__ __launch_bounds__(256) void ln_fused(
    const float* __restrict__ x, const float* __restrict__ g,
    const float* __restrict__ b, u16* __restrict__ out, int gather)
{
    int wave = threadIdx.x >> 6, lane = threadIdx.x & 63;
    int t = blockIdx.x * 4 + wave;
    int src = gather ? win_to_img_row(t) : t;
    const float* xr = x + (size_t)src * 512 + lane * 8;
    float4 a = *(const float4*)xr;
    float4 c = *(const float4*)(xr + 4);
    float s = a.x + a.y + a.z + a.w + c.x + c.y + c.z + c.w;
    float s2 = a.x*a.x + a.y*a.y + a.z*a.z + a.w*a.w
             + c.x*c.x + c.y*c.y + c.z*c.z + c.w*c.w;
#pragma unroll
    for (int off = 32; off; off >>= 1) { s += __shfl_down(s, off); s2 += __shfl_down(s2, off); }
    s = __shfl(s, 0); s2 = __shfl(s2, 0);
    float mu = s * (1.f / 512.f);
    float var = s2 * (1.f / 512.f) - mu * mu;
    float rs = rsqrtf(var + 1e-5f);
    int col = lane * 8;
    float4 g0 = *(const float4*)(g + col), g1 = *(const float4*)(g + col + 4);
    float4 b0 = *(const float4*)(b + col), b1 = *(const float4*)(b + col + 4);
    u16 r[8];
    r[0] = f2bf((a.x - mu) * rs * g0.x + b0.x);
    r[1] = f2bf((a.y - mu) * rs * g0.y + b0.y);
    r[2] = f2bf((a.z - mu) * rs * g0.z + b0.z);
    r[3] = f2bf((a.w - mu) * rs * g0.w + b0.w);
    r[4] = f2bf((c.x - mu) * rs * g1.x + b1.x);
    r[5] = f2bf((c.y - mu) * rs * g1.y + b1.y);
    r[6] = f2bf((c.z - mu) * rs * g1.z + b1.z);
    r[7] = f2bf((c.w - mu) * rs * g1.w + b1.w);
    *(uint4*)(out + (size_t)t * 512 + col) = *(const uint4*)r;
}

__global__ __launch_bounds__(256) void transpose_k(
    const float* __restrict__ W, u16* __restrict__ WT, int K, int N)
{
    int f = blockIdx.x * 256 + threadIdx.x;
    int n = f % N, kc = f / N;
    if (kc >= (K >> 3)) return;
    int k0 = kc << 3;
    u16 r[8];
#pragma unroll
    for (int j = 0; j < 8; ++j) r[j] = f2bf(W[(size_t)(k0 + j) * N + n]);
    *(uint4*)(WT + (size_t)n * K + k0) = *(const uint4*)r;
}

// ---------------------------------------------------------------------------
// MFMA GEMM, 128x128 tile, BK=64, chunk-major LDS (stride 1032 u16 = 2064 B).
// ASRC: 0 plain bf16 (async) | 3 bf16 qkv-slice gather (async).
// ---------------------------------------------------------------------------
enum { M_QKV = 0, M_PROJ = 1, M_GELU = 2, M_FINAL = 3 };

template <int MODE, int ASRC>
__global__ __launch_bounds__(256, 4) void gemm_bt(
    const u16* __restrict__ Aptr, int lda,
    const u16* __restrict__ BT, int ldb,
    const float* __restrict__ bias,
    void* __restrict__ outp, const float* __restrict__ auxf, int K)
{
    __shared__ __align__(16) u16 As[8 * 1032];
    __shared__ __align__(16) u16 Bs[8 * 1032];

    int tid = threadIdx.x;
    int bm = blockIdx.y * 128, bn = blockIdx.x * 128;
    int wave = tid >> 6, lane = tid & 63;
    int quad = lane >> 4, lr = lane & 15;
    int wm = (wave >> 1) * 64, wn = (wave & 1) * 64;

    floatx4 acc[4][4] = {};

    for (int k0 = 0; k0 < K; k0 += 64) {
#pragma unroll
        for (int l = 0; l < 4; ++l) {
            int idx = wave * 4 + l;            // 0..15
            int c = idx & 7, half = idx >> 3;
            int kk = k0 + c * 8;
            async_cp16(BT + (size_t)(bn + half * 64 + lane) * ldb + kk,
                       Bs + c * 1032 + half * 512);
            if constexpr (ASRC == 0) {
                async_cp16(Aptr + (size_t)(bm + half * 64 + lane) * lda + kk,
                           As + c * 1032 + half * 512);
            } else {  // qkv-slice gather: win uniform per half, tok = lane
                int win = (bm >> 6) + half;
                async_cp16(Aptr + (size_t)((win << 4) + (kk >> 5)) * 2048
                               + lane * 32 + (kk & 31),
                           As + c * 1032 + half * 512);
            }
        }
        __syncthreads();
#pragma unroll
        for (int step = 0; step < 2; ++step) {
            short8 af[4], bv[4];
#pragma unroll
            for (int t = 0; t < 4; ++t) {
                int kc = step * 4 + quad;
                af[t] = *(const short8*)(As + kc * 1032 + (wm + t * 16 + lr) * 8);
                bv[t] = *(const short8*)(Bs + kc * 1032 + (wn + t * 16 + lr) * 8);
            }
#pragma unroll
            for (int mt = 0; mt < 4; ++mt)
#pragma unroll
                for (int nt = 0; nt < 4; ++nt)
                    acc[mt][nt] = __builtin_amdgcn_mfma_f32_16x16x32_bf16(
                        af[mt], bv[nt], acc[mt][nt], 0, 0, 0);
        }
        __syncthreads();
    }

#pragma unroll
    for (int mt = 0; mt < 4; ++mt) {
#pragma unroll
        for (int nt = 0; nt < 4; ++nt) {
            int m0 = bm + wm + mt * 16 + quad * 4;
            int n = bn + wn + nt * 16 + lr;
#pragma unroll
            for (int i = 0; i < 4; ++i) {
                int m = m0 + i;
                float v = acc[mt][nt][i];
                if constexpr (MODE == M_QKV) {
                    v += bias[n];
                    int sel = n >> 9, head = (n >> 5) & 15, d = n & 31;
                    int wh = (m >> 6) * 16 + head, tok = m & 63;
                    ((u16*)outp)[(size_t)sel * 16777216 + (size_t)wh * 2048 + tok * 32 + d] = f2bf(v);
                } else if constexpr (MODE == M_PROJ) {
                    size_t idx = (size_t)win_to_img_row(m) * 512 + n;
                    ((float*)outp)[idx] = v + bias[n] + auxf[idx];
                } else if constexpr (MODE == M_GELU) {
                    v += bias[n];
                    float gel = 0.5f * v * (1.0f + erff(v * 0.70710678118654752f));
                    ((u16*)outp)[(size_t)m * 2048 + n] = f2bf(gel);
                } else { // M_FINAL: outp = xres f32, read-modify-write
                    size_t idx = (size_t)m * 512 + n;
                    float* o = (float*)outp;
                    o[idx] = o[idx] + v + bias[n];
                }
            }
        }
    }
}

// ---------------------------------------------------------------------------
// MFMA attention (unchanged from round 3): block = 4 waves = 4 windows x 1
// head; S = QK^T, quad-shuffle softmax, P->LDS transposed bf16, O = P V.
// Output in-place over q.
// ---------------------------------------------------------------------------
__global__ __launch_bounds__(256) void attn_mfma(
    const u16* __restrict__ qkv, const float* __restrict__ table,
    u16* __restrict__ outp)
{
    __shared__ __align__(8) u16 PT[4][64 * 76];
    __shared__ float blds[225];

    int w = threadIdx.x >> 6, lane = threadIdx.x & 63;
    int head = blockIdx.x & 15, win = ((blockIdx.x >> 4) << 2) + w;
    int wh = (win << 4) + head;
    int quad = lane >> 4, lr = lane & 15;
    const u16* qb = qkv + (size_t)wh * 2048;
    const u16* kb = qb + 16777216;
    const u16* vb = qb + 33554432;
    u16* PTw = PT[w];

    for (int i = threadIdx.x; i < 225; i += 256) blds[i] = table[i * 16 + head];
    __syncthreads();

    short8 qf[4], kf[4];
#pragma unroll
    for (int t = 0; t < 4; ++t) {
        qf[t] = *(const short8*)(qb + (t * 16 + lr) * 32 + quad * 8);
        kf[t] = *(const short8*)(kb + (t * 16 + lr) * 32 + quad * 8);
    }
    floatx4 s[4][4] = {};
#pragma unroll
    for (int mi = 0; mi < 4; ++mi)
#pragma unroll
        for (int ni = 0; ni < 4; ++ni)
            s[mi][ni] = __builtin_amdgcn_mfma_f32_16x16x32_bf16(qf[mi], kf[ni], s[mi][ni], 0, 0, 0);

    short8 vf[2][2];
#pragma unroll
    for (int ks = 0; ks < 2; ++ks)
#pragma unroll
        for (int nd = 0; nd < 2; ++nd)
#pragma unroll
            for (int j = 0; j < 8; ++j)
                vf[ks][nd][j] = (short)vb[(ks * 32 + quad * 8 + j) * 32 + nd * 16 + lr];

    int wr = (win >> 3) & 7, wc = win & 7;
    int rj[4], cj[4], regj[4];
#pragma unroll
    for (int ni = 0; ni < 4; ++ni) {
        int kj = ni * 16 + lr;
        rj[ni] = kj >> 3; cj[ni] = kj & 7;
        int hJ = wr * 8 + rj[ni], wJ = wc * 8 + cj[ni];
        regj[ni] = (hJ < 56 ? 0 : (hJ < 60 ? 1 : 2)) * 3 + (wJ < 56 ? 0 : (wJ < 60 ? 1 : 2));
    }
    float rm[4][4], linv[4][4];
#pragma unroll
    for (int mi = 0; mi < 4; ++mi) {
#pragma unroll
        for (int i = 0; i < 4; ++i) {
            int qi = mi * 16 + quad * 4 + i;
            int ri = qi >> 3, ci = qi & 7;
            int hI = wr * 8 + ri, wI = wc * 8 + ci;
            int regi = (hI < 56 ? 0 : (hI < 60 ? 1 : 2)) * 3 + (wI < 56 ? 0 : (wI < 60 ? 1 : 2));
            float mx = -1e30f;
#pragma unroll
            for (int ni = 0; ni < 4; ++ni) {
                float v = s[mi][ni][i] * 0.17677669529663687f
                        + blds[(ri - rj[ni] + 7) * 15 + (ci - cj[ni] + 7)];
                if (regj[ni] != regi) v -= 100.f;
                s[mi][ni][i] = v;
                mx = fmaxf(mx, v);
            }
            rm[mi][i] = mx;
        }
    }
#pragma unroll
    for (int mi = 0; mi < 4; ++mi)
#pragma unroll
        for (int i = 0; i < 4; ++i) {
            float mx = rm[mi][i];
#pragma unroll
            for (int msk = 1; msk < 16; msk <<= 1) mx = fmaxf(mx, __shfl_xor(mx, msk));
            float sum = 0.f;
#pragma unroll
            for (int ni = 0; ni < 4; ++ni) {
                float e = __expf(s[mi][ni][i] - mx);
                s[mi][ni][i] = e;
                sum += e;
            }
#pragma unroll
            for (int msk = 1; msk < 16; msk <<= 1) sum += __shfl_xor(sum, msk);
            linv[mi][i] = 1.f / sum;
        }

#pragma unroll
    for (int mi = 0; mi < 4; ++mi)
#pragma unroll
        for (int ni = 0; ni < 4; ++ni) {
            unsigned lo = (unsigned)f2bf(s[mi][ni][0]) | ((unsigned)f2bf(s[mi][ni][1]) << 16);
            unsigned hi = (unsigned)f2bf(s[mi][ni][2]) | ((unsigned)f2bf(s[mi][ni][3]) << 16);
            uint2 pk = make_uint2(lo, hi);
            *(uint2*)(PTw + (ni * 16 + lr) * 76 + mi * 16 + quad * 4) = pk;
        }
    __syncthreads();

    floatx4 o[4][2] = {};
#pragma unroll
    for (int mi = 0; mi < 4; ++mi) {
#pragma unroll
        for (int ks = 0; ks < 2; ++ks) {
            short8 pa;
#pragma unroll
            for (int j = 0; j < 8; ++j)
                pa[j] = (short)PTw[(ks * 32 + quad * 8 + j) * 76 + mi * 16 + lr];
#pragma unroll
            for (int nd = 0; nd < 2; ++nd)
                o[mi][nd] = __builtin_amdgcn_mfma_f32_16x16x32_bf16(pa, vf[ks][nd], o[mi][nd], 0, 0, 0);
        }
    }
    u16* ob = outp + (size_t)wh * 2048;
#pragma unroll
    for (int mi = 0; mi < 4; ++mi)
#pragma unroll
        for (int nd = 0; nd < 2; ++nd)
#pragma unroll
            for (int i = 0; i < 4; ++i) {
                int qi = mi * 16 + quad * 4 + i;
                ob[qi * 32 + nd * 16 + lr] = f2bf(o[mi][nd][i] * linv[mi][i]);
            }
}

// ---------------------------------------------------------------------------
extern "C" void kernel_launch(void* const* d_in, const int* in_sizes, int n_in,
                              void* d_out, int out_size, void* d_ws, size_t ws_size,
                              hipStream_t stream)
{
    (void)in_sizes; (void)n_in; (void)out_size; (void)ws_size;
    const float* x      = (const float*)d_in[0];
    const float* n1g    = (const float*)d_in[2];
    const float* n1b    = (const float*)d_in[3];
    const float* qkv_w  = (const float*)d_in[4];
    const float* qkv_b  = (const float*)d_in[5];
    const float* table  = (const float*)d_in[6];
    const float* proj_w = (const float*)d_in[7];
    const float* proj_b = (const float*)d_in[8];
    const float* n2g    = (const float*)d_in[9];
    const float* n2b    = (const float*)d_in[10];
    const float* fc1_w  = (const float*)d_in[11];
    const float* fc1_b  = (const float*)d_in[12];
    const float* fc2_w  = (const float*)d_in[13];
    const float* fc2_b  = (const float*)d_in[14];
    float* out = (float*)d_out;
    char* ws = (char*)d_ws;

    u16* qkvT  = (u16*)ws;                  // 786432
    u16* projT = qkvT + 786432;             // 262144
    u16* fc1T  = projT + 262144;            // 1048576
    u16* fc2T  = fc1T + 1048576;            // 1048576 (ends 6,291,456 B)
    u16* q    = (u16*)(ws + 8388608);       // q,k,v 3x32MB (ends 104 MB)
    u16* h2   = q;                          // overlays q after proj
    u16* gbuf = q + 16777216;               // 64 MB over k+v (dead post-attn)
    u16* xw   = (u16*)d_out;                // LN1+shift bf16, dead before proj

    transpose_k<<<384, 256, 0, stream>>>(qkv_w, qkvT, 512, 1536);
    transpose_k<<<128, 256, 0, stream>>>(proj_w, projT, 512, 512);
    transpose_k<<<512, 256, 0, stream>>>(fc1_w, fc1T, 512, 2048);
    transpose_k<<<512, 256, 0, stream>>>(fc2_w, fc2T, 2048, 512);

    // LN1 + shift/window gather -> xw (in d_out)
    ln_fused<<<8192, 256, 0, stream>>>(x, n1g, n1b, xw, 1);
    // QKV from xw
    gemm_bt<M_QKV, 0><<<dim3(12, 256), 256, 0, stream>>>(
        xw, 512, qkvT, 512, qkv_b, q, nullptr, 512);
    attn_mfma<<<2048, 256, 0, stream>>>(q, table, q);
    // proj + reverse-shift scatter + residual -> d_out (overwrites xw fully)
    gemm_bt<M_PROJ, 3><<<dim3(4, 256), 256, 0, stream>>>(
        q, 0, projT, 512, proj_b, out, x, 512);
    // LN2 -> h2
    ln_fused<<<8192, 256, 0, stream>>>(out, n2g, n2b, h2, 0);
    for (int mc = 0; mc < 2; ++mc) {
        gemm_bt<M_GELU, 0><<<dim3(16, 128), 256, 0, stream>>>(
            h2 + (size_t)mc * 16384 * 512, 512, fc1T, 512, fc1_b,
            gbuf, nullptr, 512);
        gemm_bt<M_FINAL, 0><<<dim3(4, 128), 256, 0, stream>>>(
            gbuf, 2048, fc2T, 2048, fc2_b,
            out + (size_t)mc * 16384 * 512, nullptr, 2048);
    }
}